// Round 1
// baseline (99.177 us; speedup 1.0000x reference)
//
#include <hip/hip_runtime.h>

#define BATCH 128
#define TLEN  160000
#define NSEG  200

// Kernel 0: per-row sequential scan over 200 segments -> [start,end) intervals.
// One thread per batch row; 200 iterations each. Replicates reference math in
// int32/float32 exactly.
__global__ void pl_segments(const float* __restrict__ ratio,
                            const int* __restrict__ seg_len_raw,
                            const float* __restrict__ start_u,
                            int* __restrict__ seg_start,
                            int* __restrict__ seg_end) {
    int b = blockIdx.x * blockDim.x + threadIdx.x;
    if (b >= BATCH) return;
    // total = int(floor(T * ratio)) in float32, like jnp.floor(t*ratio).astype(int32)
    int total = (int)floorf((float)TLEN * ratio[b]);
    int prev = 0;
    const int base = b * NSEG;
    for (int s = 0; s < NSEG; ++s) {
        int len = seg_len_raw[base + s];
        int rem = total - prev;
        int eff = rem < 0 ? 0 : (rem > len ? len : rem);   // clip(total-prev, 0, len)
        prev += len;
        float u = start_u[base + s];
        int start = (int)floorf(u * (float)(TLEN - eff + 1));
        seg_start[base + s] = start;
        seg_end[base + s]   = start + eff;
    }
}

// Kernel 1: vectorized copy audio -> out (float4, grid-stride).
__global__ void pl_copy(const float4* __restrict__ in, float4* __restrict__ out, int n4) {
    int i = blockIdx.x * blockDim.x + threadIdx.x;
    int stride = gridDim.x * blockDim.x;
    for (; i < n4; i += stride) out[i] = in[i];
}

// Kernel 2: one block per (b,seg); zero out[b, start:end). Zero-length segs no-op.
__global__ void pl_zero(const int* __restrict__ seg_start,
                        const int* __restrict__ seg_end,
                        float* __restrict__ out) {
    int idx = blockIdx.x;                 // b*NSEG + s
    int b = idx / NSEG;
    int s0 = seg_start[idx];
    int s1 = seg_end[idx];
    float* row = out + (size_t)b * TLEN;
    for (int i = s0 + (int)threadIdx.x; i < s1; i += (int)blockDim.x)
        row[i] = 0.0f;
}

extern "C" void kernel_launch(void* const* d_in, const int* in_sizes, int n_in,
                              void* d_out, int out_size, void* d_ws, size_t ws_size,
                              hipStream_t stream) {
    const float* audio       = (const float*)d_in[0];
    const float* ratio       = (const float*)d_in[1];
    const int*   seg_len_raw = (const int*)d_in[2];
    const float* start_u     = (const float*)d_in[3];
    float* out = (float*)d_out;

    int* seg_start = (int*)d_ws;                    // BATCH*NSEG ints
    int* seg_end   = seg_start + BATCH * NSEG;      // BATCH*NSEG ints

    // 1) compute intervals
    pl_segments<<<1, 128, 0, stream>>>(ratio, seg_len_raw, start_u, seg_start, seg_end);

    // 2) copy audio -> out
    const int n4 = BATCH * TLEN / 4;                // 5,120,000 float4s
    pl_copy<<<2048, 256, 0, stream>>>((const float4*)audio, (float4*)out, n4);

    // 3) scatter-zero the segments
    pl_zero<<<BATCH * NSEG, 256, 0, stream>>>(seg_start, seg_end, out);
}

// Round 2
// 44.178 us; speedup vs baseline: 2.2450x; 2.2450x over previous
//
#include <hip/hip_runtime.h>

#define BATCH 128
#define TLEN  160000
#define NSEG  200

// Kernel 0: one block per batch row. Coalesced load of 200 segment lengths,
// LDS Hillis-Steele inclusive scan, then per-thread eff/start/end computation.
__global__ void pl_segments(const float* __restrict__ ratio,
                            const int* __restrict__ seg_len_raw,
                            const float* __restrict__ start_u,
                            int* __restrict__ seg_start,
                            int* __restrict__ seg_end) {
    const int b   = blockIdx.x;
    const int tid = threadIdx.x;
    __shared__ int sdata[256];

    const int base = b * NSEG;
    int len = (tid < NSEG) ? seg_len_raw[base + tid] : 0;

    // inclusive scan over 256 entries (entries >= NSEG are 0)
    sdata[tid] = len;
    __syncthreads();
    #pragma unroll
    for (int off = 1; off < 256; off <<= 1) {
        int t = (tid >= off) ? sdata[tid - off] : 0;
        __syncthreads();
        sdata[tid] += t;
        __syncthreads();
    }

    if (tid < NSEG) {
        // total = int(floor(T * ratio)) in float32 (matches reference)
        int total = (int)floorf((float)TLEN * ratio[b]);
        int prev  = sdata[tid] - len;                     // exclusive prefix
        int rem   = total - prev;
        int eff   = rem < 0 ? 0 : (rem > len ? len : rem); // clip(total-prev,0,len)
        float u   = start_u[base + tid];
        int start = (int)floorf(u * (float)(TLEN - eff + 1));
        seg_start[base + tid] = start;
        seg_end[base + tid]   = start + eff;
    }
}

// Kernel 1: vectorized copy audio -> out (float4, grid-stride).
__global__ void pl_copy(const float4* __restrict__ in, float4* __restrict__ out, int n4) {
    int i = blockIdx.x * blockDim.x + threadIdx.x;
    int stride = gridDim.x * blockDim.x;
    for (; i < n4; i += stride) out[i] = in[i];
}

// Kernel 2: one block per (b,seg); zero out[b, start:end). Zero-length segs no-op.
__global__ void pl_zero(const int* __restrict__ seg_start,
                        const int* __restrict__ seg_end,
                        float* __restrict__ out) {
    int idx = blockIdx.x;                 // b*NSEG + s
    int b = idx / NSEG;
    int s0 = seg_start[idx];
    int s1 = seg_end[idx];
    float* row = out + (size_t)b * TLEN;
    for (int i = s0 + (int)threadIdx.x; i < s1; i += (int)blockDim.x)
        row[i] = 0.0f;
}

extern "C" void kernel_launch(void* const* d_in, const int* in_sizes, int n_in,
                              void* d_out, int out_size, void* d_ws, size_t ws_size,
                              hipStream_t stream) {
    const float* audio       = (const float*)d_in[0];
    const float* ratio       = (const float*)d_in[1];
    const int*   seg_len_raw = (const int*)d_in[2];
    const float* start_u     = (const float*)d_in[3];
    float* out = (float*)d_out;

    int* seg_start = (int*)d_ws;                    // BATCH*NSEG ints
    int* seg_end   = seg_start + BATCH * NSEG;      // BATCH*NSEG ints

    // 1) compute intervals (one block per row, parallel scan)
    pl_segments<<<BATCH, 256, 0, stream>>>(ratio, seg_len_raw, start_u, seg_start, seg_end);

    // 2) copy audio -> out
    const int n4 = BATCH * TLEN / 4;                // 5,120,000 float4s
    pl_copy<<<2048, 256, 0, stream>>>((const float4*)audio, (float4*)out, n4);

    // 3) scatter-zero the segments
    pl_zero<<<BATCH * NSEG, 256, 0, stream>>>(seg_start, seg_end, out);
}